// Round 5
// baseline (36579.562 us; speedup 1.0000x reference)
//
#include <hip/hip_runtime.h>
#include <hip/hip_bf16.h>
#include <math.h>

// Problem constants
#define TY 128
#define B  64
#define TX 400
#define IN 512
#define H  512
#define C  512
#define NH 8
#define DH 64
#define G4 2048   // 4*H
#define NBLK 256  // persistent grid: 1 block/CU guaranteed co-resident
#define NLEAF 32
#define LEAFSZ (NBLK / NLEAF)   // 8

__device__ __forceinline__ float sigf(float x) { return 1.f / (1.f + __expf(-x)); }

// ---------------------------------------------------------------------------
// Grid barrier: monotonic counters + tree release. bar words: leaf counters
// at i*32 (i<32); root at 1024; root-gen at 1088; per-leaf release words at
// 2048 + i*32. Zeroed per launch by k_zero_bar. Spin-reads use atomicAdd(p,0)
// (device-scope coherent across XCDs).
// ---------------------------------------------------------------------------
__device__ __forceinline__ void gsync(unsigned* bar, unsigned round) {
  __syncthreads();
  if (threadIdx.x == 0) {
    __threadfence();
    int leafId = (int)(blockIdx.x & (NLEAF - 1));
    unsigned a = atomicAdd(bar + leafId * 32, 1u) + 1u;
    if (a == round * LEAFSZ) {
      unsigned r = atomicAdd(bar + 1024, 1u) + 1u;
      if (r == round * NLEAF) {
        atomicExch(bar + 1088, round);
      }
      while (atomicAdd(bar + 1088, 0u) < round) __builtin_amdgcn_s_sleep(2);
      atomicExch(bar + 2048 + leafId * 32, round);
    } else {
      while (atomicAdd(bar + 2048 + leafId * 32, 0u) < round)
        __builtin_amdgcn_s_sleep(2);
    }
    __threadfence();
  }
  __syncthreads();
}

__global__ __launch_bounds__(256) void k_zero_bar(unsigned* bar) {
  int i = blockIdx.x * 256 + threadIdx.x;
  if (i < 4096) bar[i] = 0u;
}

// ---------------------------------------------------------------------------
// Precompute GEMM: Out[r,n] = sum_k A[r,k]*W[n,k] + bias1[n] (+bias2[n])
// ---------------------------------------------------------------------------
__global__ __launch_bounds__(256) void gemm_bias(
    const float* __restrict__ A, const float* __restrict__ W,
    const float* __restrict__ bias1, const float* __restrict__ bias2,
    float* __restrict__ Out, int N, int K) {
  __shared__ float As[16][68];
  __shared__ float Ws[16][68];
  int tid = threadIdx.x;
  int n0 = blockIdx.x * 64;
  int r0 = blockIdx.y * 64;
  int tx = tid & 15, ty = tid >> 4;
  float acc[4][4] = {};
  for (int k0 = 0; k0 < K; k0 += 16) {
    #pragma unroll
    for (int i = 0; i < 4; i++) {
      int idx = tid + i * 256;
      int r = idx >> 4, k = idx & 15;
      As[k][r] = A[(size_t)(r0 + r) * K + k0 + k];
      Ws[k][r] = W[(size_t)(n0 + r) * K + k0 + k];
    }
    __syncthreads();
    #pragma unroll
    for (int k = 0; k < 16; k++) {
      float a[4], w[4];
      #pragma unroll
      for (int i = 0; i < 4; i++) a[i] = As[k][ty * 4 + i];
      #pragma unroll
      for (int j = 0; j < 4; j++) w[j] = Ws[k][tx * 4 + j];
      #pragma unroll
      for (int i = 0; i < 4; i++)
        #pragma unroll
        for (int j = 0; j < 4; j++) acc[i][j] += a[i] * w[j];
    }
    __syncthreads();
  }
  #pragma unroll
  for (int i = 0; i < 4; i++) {
    int r = r0 + ty * 4 + i;
    #pragma unroll
    for (int j = 0; j < 4; j++) {
      int n = n0 + tx * 4 + j;
      float v = acc[i][j];
      if (bias1) v += bias1[n];
      if (bias2) v += bias2[n];
      Out[(size_t)r * N + n] = v;
    }
  }
}

// ---------------------------------------------------------------------------
// noinline phase functions (own static LDS; barriers at block-uniform points)
// ---------------------------------------------------------------------------

// 64x64 GEMM tile over a K-slice. A(r,kk) = kk<512 ? A1[...] : A2[...].
__device__ __attribute__((noinline)) void tile_gemm(
    const float* A1, const float* A2, const float* W,
    int Ktot, int kbeg, int kcnt, int n0,
    float* outBase, int ldo, int atomicOut) {
  __shared__ float As[16][68];
  __shared__ float Ws[16][68];
  int tid = threadIdx.x;
  int tx = tid & 15, ty = tid >> 4;
  float acc[4][4] = {};
  for (int k0 = kbeg; k0 < kbeg + kcnt; k0 += 16) {
    __syncthreads();
    #pragma unroll
    for (int i = 0; i < 4; i++) {
      int idx = tid + i * 256;
      int r = idx >> 4, k = idx & 15;
      int kk = k0 + k;
      float av = (kk < 512) ? A1[r * 512 + kk] : A2[r * 512 + kk - 512];
      As[k][r] = av;
      Ws[k][r] = W[(size_t)(n0 + r) * Ktot + kk];
    }
    __syncthreads();
    #pragma unroll
    for (int k = 0; k < 16; k++) {
      float a[4], w[4];
      #pragma unroll
      for (int i = 0; i < 4; i++) a[i] = As[k][ty * 4 + i];
      #pragma unroll
      for (int j = 0; j < 4; j++) w[j] = Ws[k][tx * 4 + j];
      #pragma unroll
      for (int i = 0; i < 4; i++)
        #pragma unroll
        for (int j = 0; j < 4; j++) acc[i][j] += a[i] * w[j];
    }
  }
  #pragma unroll
  for (int i = 0; i < 4; i++) {
    int b = ty * 4 + i;
    #pragma unroll
    for (int j = 0; j < 4; j++) {
      int n = n0 + tx * 4 + j;
      if (atomicOut) atomicAdd(&outBase[b * ldo + n], acc[i][j]);
      else outBase[b * ldo + n] = acc[i][j];
    }
  }
}

// LSTM cell for step t. bi in [0,128) x 256 threads = 32768 = B*H.
__device__ __attribute__((noinline)) void cell_fn(
    const float* xW_all, const float* gatesP, const float* hp,
    const float* cp, const float* y_mask,
    float* hs, float* cs, float* ss, int t, int bi, int tid) {
  int idx = bi * 256 + tid;
  int b = idx >> 9, m = idx & 511;
  const float* xWt = xW_all + (size_t)t * B * G4;
  float g4v[4];
  #pragma unroll
  for (int q = 0; q < 4; q++) {
    int j = q * 512 + m;
    float g = xWt[b * G4 + j];
    #pragma unroll
    for (int s = 0; s < 4; s++) g += gatesP[(size_t)(s * 64 + b) * G4 + j];
    g4v[q] = g;
  }
  float i_ = sigf(g4v[0]);
  float f_ = sigf(g4v[1]);
  float gg = tanhf(g4v[2]);
  float o_ = sigf(g4v[3]);
  float cpv = cp[idx], hpv = hp[idx];
  float c1 = f_ * cpv + i_ * gg;
  float h1 = o_ * tanhf(c1);
  float ym = y_mask[t * B + b];
  h1 = ym * h1 + (1.f - ym) * hpv;
  c1 = ym * c1 + (1.f - ym) * cpv;
  size_t o = (size_t)t * B * H + idx;
  hs[o] = h1;
  ss[o] = h1;
  cs[o] = c1;
}

// e scores. bid in [0,192): 768 waves; wave owns fixed b, strides over t.
__device__ __attribute__((noinline)) void e_fn(
    const float* pctx, const float* hq, const float* accbuf,
    const float* W_cov, const float* U_att, const float* x_mask,
    float* ebuf, int bid, int tid) {
  int wv = tid >> 6, lane = tid & 63;
  int wid = bid * 4 + wv;      // 0..767
  int b = wid & 63;            // stride 768 = 12*64 keeps b invariant
  float hqv[8], wcv[8], uv[8];
  #pragma unroll
  for (int h = 0; h < 8; h++) {
    int c = h * 64 + lane;
    hqv[h] = hq[b * C + c];
    wcv[h] = W_cov[c];
    uv[h]  = U_att[h * 64 + lane];
  }
  for (int pair = wid; pair < TX * B; pair += 768) {
    int t = pair >> 6;
    const float* prow = pctx + (size_t)pair * C;
    float a = accbuf[b * TX + t];
    float xm = x_mask[pair];
    float v[8];
    #pragma unroll
    for (int h = 0; h < 8; h++) {
      float u = tanhf(prow[h * 64 + lane] + hqv[h] + a * wcv[h]);
      v[h] = u * uv[h];
    }
    #pragma unroll
    for (int off = 32; off; off >>= 1)
      #pragma unroll
      for (int h = 0; h < 8; h++) v[h] += __shfl_xor(v[h], off);
    if (lane == 0) {
      float* ep = ebuf + (size_t)(b * 8) * TX + t;
      #pragma unroll
      for (int h = 0; h < 8; h++) ep[h * TX] = v[h] * xm;
    }
  }
}

// softmax over t for one (b,h)=bh; h==0 also dist/Cs/coverage.
__device__ __attribute__((noinline)) void softmax_fn(
    const float* ebuf, const float* x_mask, float* wbuf, float* accbuf,
    float* dist, float* Cso, int bh, int tid) {
  __shared__ float s_red[8];
  int b = bh >> 3, h = bh & 7;
  const float* erow = ebuf + (size_t)bh * TX;
  float* wrow = wbuf + (size_t)bh * TX;
  int wv = tid >> 6, lane = tid & 63;
  float e0 = (tid < TX) ? erow[tid] : -1e30f;
  float e1 = (tid + 256 < TX) ? erow[tid + 256] : -1e30f;
  float m = fmaxf(e0, e1);
  #pragma unroll
  for (int off = 32; off; off >>= 1) m = fmaxf(m, __shfl_xor(m, off));
  if (lane == 0) s_red[wv] = m;
  __syncthreads();
  m = fmaxf(fmaxf(s_red[0], s_red[1]), fmaxf(s_red[2], s_red[3]));
  float xm0 = (tid < TX) ? x_mask[tid * 64 + b] : 0.f;
  float xm1 = (tid + 256 < TX) ? x_mask[(tid + 256) * 64 + b] : 0.f;
  float w0 = (tid < TX) ? __expf(e0 - m) * xm0 : 0.f;
  float w1 = (tid + 256 < TX) ? __expf(e1 - m) * xm1 : 0.f;
  float s = w0 + w1;
  #pragma unroll
  for (int off = 32; off; off >>= 1) s += __shfl_xor(s, off);
  if (lane == 0) s_red[4 + wv] = s;
  __syncthreads();
  s = s_red[4] + s_red[5] + s_red[6] + s_red[7] + 1e-6f;
  float inv = 1.f / s;
  w0 *= inv; w1 *= inv;
  if (tid < TX) wrow[tid] = w0;
  if (tid + 256 < TX) wrow[tid + 256] = w1;
  if (h == 0) {
    if (tid < TX) {
      float a = accbuf[b * TX + tid];
      dist[b * TX + tid] = w0;
      Cso[b * TX + tid] = a;
      accbuf[b * TX + tid] = a + w0;
    }
    if (tid + 256 < TX) {
      float a = accbuf[b * TX + tid + 256];
      dist[b * TX + tid + 256] = w1;
      Cso[b * TX + tid + 256] = a;
      accbuf[b * TX + tid + 256] = a + w1;
    }
  }
  __syncthreads();
}

// Fused attention-sum + concat-projection + LayerNorm for batch row b.
__device__ __attribute__((noinline)) void att_fn(
    const float* wbuf, const float* pv, const float* W_cat,
    const float* ln_g, const float* ln_b, float* ao, int b, int tid) {
  __shared__ float s_part[4 * 512];
  __shared__ float s_att[512];
  __shared__ float s_o[512];
  __shared__ float s_red[8];
  int wv = tid >> 6, lane = tid & 63;
  float av[8] = {};
  for (int tx = wv; tx < TX; tx += 4) {
    const float* pvrow = pv + (size_t)(tx * 64 + b) * C;
    #pragma unroll
    for (int h = 0; h < 8; h++) {
      float wt = wbuf[(size_t)(b * 8 + h) * TX + tx];
      av[h] += wt * pvrow[h * 64 + lane];
    }
  }
  #pragma unroll
  for (int h = 0; h < 8; h++) s_part[wv * 512 + h * 64 + lane] = av[h];
  __syncthreads();
  float x0 = s_part[tid] + s_part[512 + tid] + s_part[1024 + tid] + s_part[1536 + tid];
  float x1 = s_part[tid + 256] + s_part[512 + tid + 256] +
             s_part[1024 + tid + 256] + s_part[1536 + tid + 256];
  s_att[tid] = x0;
  s_att[tid + 256] = x1;
  __syncthreads();
  for (int j = wv; j < 512; j += 4) {
    const float* wr = W_cat + (size_t)j * 512;
    float pp = 0.f;
    #pragma unroll
    for (int q = 0; q < 8; q++) pp += s_att[q * 64 + lane] * wr[q * 64 + lane];
    #pragma unroll
    for (int off = 32; off; off >>= 1) pp += __shfl_xor(pp, off);
    if (lane == 0) s_o[j] = pp;
  }
  __syncthreads();
  float y0 = s_o[tid], y1 = s_o[tid + 256];
  float sum = y0 + y1, sq = y0 * y0 + y1 * y1;
  #pragma unroll
  for (int off = 32; off; off >>= 1) {
    sum += __shfl_xor(sum, off);
    sq += __shfl_xor(sq, off);
  }
  if (lane == 0) { s_red[wv] = sum; s_red[4 + wv] = sq; }
  __syncthreads();
  sum = s_red[0] + s_red[1] + s_red[2] + s_red[3];
  sq = s_red[4] + s_red[5] + s_red[6] + s_red[7];
  float mu = sum * (1.f / 512.f);
  float var = sq * (1.f / 512.f) - mu * mu;
  float rstd = rsqrtf(var + 1e-5f);
  ao[tid] = (y0 - mu) * rstd * ln_g[tid] + ln_b[tid];
  ao[tid + 256] = (y1 - mu) * rstd * ln_g[tid + 256] + ln_b[tid + 256];
}

// ---------------------------------------------------------------------------
// Persistent mega-kernel (plain launch, 256 blocks = 1/CU, own barrier).
// 4 grid syncs per step.
// ---------------------------------------------------------------------------
__global__ __launch_bounds__(256) void mega(
    const float* h0, const float* c0, const float* x_mask,
    const float* y_mask, const float* init_cov,
    const float* W_hh, const float* W_comb, const float* U_att,
    const float* W_cov, const float* W_cat, const float* ln_g,
    const float* ln_b,
    const float* pctx, const float* pv, const float* xW,
    float* gatesP, float* hq, float* ebuf, float* wbuf, float* accbuf,
    float* hs, float* cs, float* ss, float* atts, float* dists, float* Cs,
    unsigned* bar) {
  const int bid = blockIdx.x;
  const int tid = threadIdx.x;
  unsigned rnd = 0;

  // ---- prologue: hq<-0 (all blocks), gates(0), acc <- init_cov ----
  if (tid < 128) hq[bid * 128 + tid] = 0.f;   // 256*128 = 32768 = B*C
  if (bid < 128) {
    int colTile = bid & 31, slice = bid >> 5;
    tile_gemm(h0, nullptr, W_hh, 512, slice * 128, 128,
              colTile * 64, gatesP + (size_t)slice * 64 * G4, G4, 0);
  } else if (bid < 228) {
    int i = (bid - 128) * 256 + tid;
    accbuf[i] = init_cov[i];
  }
  gsync(bar, ++rnd);
  if (bid < 128) cell_fn(xW, gatesP, h0, c0, y_mask, hs, cs, ss, 0, bid, tid);
  gsync(bar, ++rnd);

  for (int t = 0; t < TY; t++) {
    // phase A: hq GEMM (split-K atomics into zeroed hq), 64 blocks
    if (bid < 64) {
      int colTile = bid & 7, slice = bid >> 3;
      tile_gemm(hs + (size_t)t * B * H, cs + (size_t)t * B * H, W_comb, 1024,
                slice * 128, 128, colTile * 64, hq, C, 1);
    }
    gsync(bar, ++rnd);
    // phase B: e scores (t) on 192 blocks  ||  gates GEMM (t+1) on 64 blocks
    if (bid < 192) {
      e_fn(pctx, hq, accbuf, W_cov, U_att, x_mask, ebuf, bid, tid);
    } else if (t < TY - 1) {
      for (int jj = bid - 192; jj < 128; jj += 64) {
        int colTile = jj & 31, slice = jj >> 5;
        tile_gemm(hs + (size_t)t * B * H, nullptr, W_hh, 512, slice * 128,
                  128, colTile * 64, gatesP + (size_t)slice * 64 * G4, G4, 0);
      }
    }
    gsync(bar, ++rnd);
    // phase C: hq re-zero + softmax (2 bh jobs per block) + coverage
    if (tid < 128) hq[bid * 128 + tid] = 0.f;
    softmax_fn(ebuf, x_mask, wbuf, accbuf,
               dists + (size_t)t * B * TX, Cs + (size_t)t * B * TX, bid, tid);
    softmax_fn(ebuf, x_mask, wbuf, accbuf,
               dists + (size_t)t * B * TX, Cs + (size_t)t * B * TX,
               bid + 256, tid);
    gsync(bar, ++rnd);
    // phase D: att+concat+LN (t) on 64 blocks  ||  cell (t+1) on 128 blocks
    if (bid < 64) {
      att_fn(wbuf, pv, W_cat, ln_g, ln_b,
             atts + (size_t)t * B * C + (size_t)bid * C, bid, tid);
    } else if (bid < 192 && t < TY - 1) {
      cell_fn(xW, gatesP, hs + (size_t)t * B * H, cs + (size_t)t * B * H,
              y_mask, hs, cs, ss, t + 1, bid - 64, tid);
    }
    gsync(bar, ++rnd);
  }
}

// ---------------------------------------------------------------------------
extern "C" void kernel_launch(void* const* d_in, const int* in_sizes, int n_in,
                              void* d_out, int out_size, void* d_ws, size_t ws_size,
                              hipStream_t stream) {
  const float* y_emb    = (const float*)d_in[0];
  const float* context  = (const float*)d_in[1];
  const float* h0       = (const float*)d_in[2];
  const float* c0       = (const float*)d_in[3];
  const float* x_mask   = (const float*)d_in[4];
  const float* y_mask   = (const float*)d_in[5];
  const float* init_cov = (const float*)d_in[6];
  const float* W_ih     = (const float*)d_in[7];
  const float* W_hh     = (const float*)d_in[8];
  const float* b_ih     = (const float*)d_in[9];
  const float* b_hh     = (const float*)d_in[10];
  const float* Wc_att   = (const float*)d_in[11];
  const float* b_att    = (const float*)d_in[12];
  const float* Wv_att   = (const float*)d_in[13];
  const float* bv_att   = (const float*)d_in[14];
  const float* W_comb   = (const float*)d_in[15];
  const float* U_att    = (const float*)d_in[16];
  const float* W_cov    = (const float*)d_in[17];
  const float* W_cat    = (const float*)d_in[18];
  const float* ln_g     = (const float*)d_in[19];
  const float* ln_b     = (const float*)d_in[20];

  float* out = (float*)d_out;
  const size_t SZ_H = (size_t)TY * B * H;
  const size_t SZ_D = (size_t)TY * B * TX;
  float* hs    = out;
  float* cs    = out + SZ_H;
  float* ss    = out + 2 * SZ_H;
  float* atts  = out + 3 * SZ_H;
  float* dists = out + 4 * SZ_H;
  float* Cs    = out + 4 * SZ_H + SZ_D;

  float* ws = (float*)d_ws;
  size_t off = 0;
  float* pctx   = ws + off; off += (size_t)TX * B * C;
  float* pv     = ws + off; off += (size_t)TX * B * C;
  float* xW     = ws + off; off += (size_t)TY * B * G4;
  float* gatesP = ws + off; off += (size_t)4 * B * G4;
  float* hq     = ws + off; off += (size_t)B * C;
  float* ebuf   = ws + off; off += (size_t)B * NH * TX;
  float* wbuf   = ws + off; off += (size_t)B * NH * TX;
  float* accbuf = ws + off; off += (size_t)B * TX;
  unsigned* bar = (unsigned*)(ws + off); off += 4096;

  // ---- barrier init (ws is re-poisoned before every call) ----
  k_zero_bar<<<16, 256, 0, stream>>>(bar);

  // ---- precompute (independent of the recurrence) ----
  gemm_bias<<<dim3(C / 64, TX * B / 64), 256, 0, stream>>>(
      context, Wc_att, b_att, nullptr, pctx, C, C);
  gemm_bias<<<dim3(C / 64, TX * B / 64), 256, 0, stream>>>(
      context, Wv_att, bv_att, nullptr, pv, C, C);
  gemm_bias<<<dim3(G4 / 64, TY * B / 64), 256, 0, stream>>>(
      y_emb, W_ih, b_ih, b_hh, xW, G4, IN);

  // ---- persistent mega-kernel for the 128-step recurrence ----
  mega<<<dim3(NBLK), dim3(256), 0, stream>>>(
      h0, c0, x_mask, y_mask, init_cov,
      W_hh, W_comb, U_att, W_cov, W_cat, ln_g, ln_b,
      pctx, pv, xW,
      gatesP, hq, ebuf, wbuf, accbuf,
      hs, cs, ss, atts, dists, Cs, bar);
}